// Round 5
// baseline (930.862 us; speedup 1.0000x reference)
//
#include <hip/hip_runtime.h>
#include <hip/hip_bf16.h>

#define E_EDGES   800000
#define NN_NODES  50000
#define NODE_DIM  128
#define EDGE_DIM  64
#define KDIM      320
#define NTOT      256      // val(128) || gate(128)
#define BM        128      // edges per M-chunk
#define BK        64       // K chunk
#define THREADS   512
#define NPB       32       // receiver nodes owned per block
#define NPAD      50048    // NPB * 1564 (node-range padding)
#define NBLOCKS   1564
#define ACCS      132      // acc LDS row stride (f32)

typedef _Float16 half8 __attribute__((ext_vector_type(8)));
typedef float    f32x4 __attribute__((ext_vector_type(4)));

__device__ __forceinline__ unsigned short f2h(float f) {
    _Float16 h = (_Float16)f;
    return __builtin_bit_cast(unsigned short, h);
}

// async global -> LDS, 16 B per lane; dest must be wave-uniform base + lane*16
__device__ __forceinline__ void gl_lds16(const void* g, void* l) {
    __builtin_amdgcn_global_load_lds(
        (const __attribute__((address_space(1))) unsigned int*)g,
        (__attribute__((address_space(3))) unsigned int*)l,
        16, 0, 0);
}

// ---- cast x and W_val||W_mul fp32 -> f16 ----
__global__ void cast_all_kernel(const float* __restrict__ x,
                                const float* __restrict__ wv,
                                const float* __restrict__ wm,
                                unsigned short* __restrict__ xh,
                                unsigned short* __restrict__ wc) {
    const int n4x = (NN_NODES * NODE_DIM) / 4;
    const int n4h = (NODE_DIM * KDIM) / 4;
    int i = blockIdx.x * blockDim.x + threadIdx.x;
    if (i < n4x) {
        float4 f = ((const float4*)x)[i];
        ushort4 o;
        o.x = f2h(f.x); o.y = f2h(f.y); o.z = f2h(f.z); o.w = f2h(f.w);
        ((ushort4*)xh)[i] = o;
    } else {
        int k = i - n4x;
        if (k >= 2 * n4h) return;
        const float* src = (k < n4h) ? wv : wm;
        int j = (k < n4h) ? k : k - n4h;
        float4 f = ((const float4*)src)[j];
        ushort4 o;
        o.x = f2h(f.x); o.y = f2h(f.y); o.z = f2h(f.z); o.w = f2h(f.w);
        ((ushort4*)wc)[k] = o;
    }
}

// ---- counting sort by receiver: histogram ----
__global__ void hist_kernel(const int* __restrict__ ei, int* __restrict__ hist) {
    int e = blockIdx.x * blockDim.x + threadIdx.x;
    if (e < E_EDGES) atomicAdd(&hist[ei[E_EDGES + e]], 1);
}

// ---- exclusive scan over NPAD counts (single 1024-thread block) ----
__global__ void __launch_bounds__(1024)
scan_kernel(const int* __restrict__ hist, int* __restrict__ row_ptr,
            int* __restrict__ nxt) {
    __shared__ int buf[1024];
    __shared__ int carryS;
    const int t = threadIdx.x;
    if (t == 0) carryS = 0;
    __syncthreads();
    for (int base = 0; base < NPAD; base += 1024) {
        int v = (base + t < NPAD) ? hist[base + t] : 0;
        buf[t] = v;
        __syncthreads();
        for (int off = 1; off < 1024; off <<= 1) {
            int add = (t >= off) ? buf[t - off] : 0;
            __syncthreads();
            buf[t] += add;
            __syncthreads();
        }
        int incl = buf[t];
        int c = carryS;
        int excl = c + incl - v;
        if (base + t < NPAD) { row_ptr[base + t] = excl; nxt[base + t] = excl; }
        __syncthreads();
        if (t == 1023) carryS = c + incl;
        __syncthreads();
    }
    if (t == 0) row_ptr[NPAD] = carryS;   // = E_EDGES
}

// ---- scatter edge ids into receiver-sorted order ----
__global__ void scatter_kernel(const int* __restrict__ ei, int* __restrict__ nxt,
                               int* __restrict__ perm) {
    int e = blockIdx.x * blockDim.x + threadIdx.x;
    if (e < E_EDGES) {
        int r = ei[E_EDGES + e];
        int pos = atomicAdd(&nxt[r], 1);
        perm[pos] = e;
    }
}

// ---- main: gather + dual-GEMM + activation + OWNED reduction (no global atomics) ----
// Block b owns receiver nodes [32b, 32b+32); processes its CSR edge range in
// 128-edge M-chunks through the proven R4 K-loop (swizzled global_load_lds).
// Per-chunk epilogue run-merges consecutive same-receiver rows in-lane, then
// ds_add_f32 into a 32x128 LDS accumulator; final tile stored once. This cuts
// WRITE_SIZE 400 MB (write-through atomic RMWs, the R2-R4 invariant) -> 25.6 MB.
__global__ void __launch_bounds__(THREADS, 4)
cgc_main(const unsigned short* __restrict__ xh,   // [NN][128] f16 bits
         const int* __restrict__ ei,              // [2][E]
         const float* __restrict__ ef,            // [E][64] fp32
         const unsigned short* __restrict__ Wc,   // [256][320] f16 bits
         const float* __restrict__ bval,
         const float* __restrict__ bmul,
         const int* __restrict__ row_ptr,         // [NPAD+1]
         const int* __restrict__ perm,            // [E]
         float* __restrict__ out)                 // [NN][128] fp32
{
    __shared__ unsigned short As[BM * BK];    // 16 KB
    __shared__ unsigned short Bs[NTOT * BK];  // 32 KB
    __shared__ float accS[NPB * ACCS];        // 16.5 KB
    __shared__ int sE[BM];                    // sender node per row
    __shared__ int rN[BM];                    // receiver node (clamped) per row
    __shared__ int lnE[BM];                   // local node id, -1 = invalid row
    __shared__ int eID[BM];                   // original edge id (0 if invalid)

    const int tid  = threadIdx.x;
    const int lane = tid & 63;
    const int wid  = tid >> 6;
    const int wm   = wid & 1;
    const int wn   = wid >> 1;
    const int q    = lane >> 4;
    const int l16  = lane & 15;

    const int nodeBase = blockIdx.x * NPB;
    const int eStart = row_ptr[nodeBase];
    const int eEnd   = row_ptr[nodeBase + NPB];

    // zero node accumulator
#pragma unroll
    for (int i = 0; i < 9; ++i) {
        int u = tid + i * THREADS;
        if (u < NPB * ACCS) accS[u] = 0.f;
    }

    const f32x4 zero4 = {0.f, 0.f, 0.f, 0.f};

    for (int ec = eStart; ec < eEnd; ec += BM) {
        __syncthreads();   // prev epilogue done with lnE; accS zero done (1st iter)
        if (tid < BM) {
            int i = ec + tid;
            if (i < eEnd) {
                int p = perm[i];
                eID[tid] = p;
                sE[tid]  = ei[p];
                int r    = ei[E_EDGES + p];
                rN[tid]  = r;
                lnE[tid] = r - nodeBase;
            } else {
                eID[tid] = 0; sE[tid] = 0; rN[tid] = 0; lnE[tid] = -1;
            }
        }

        f32x4 acc[4][4];
#pragma unroll
        for (int mt = 0; mt < 4; ++mt)
#pragma unroll
            for (int nt = 0; nt < 4; ++nt) acc[mt][nt] = zero4;

        for (int c = 0; c < 5; ++c) {
            __syncthreads();   // c=0: indices ready; c>0: prev compute done
            // ---- stage A: 128 rows x 64 k ----
            if (c < 4) {
                const int kcol = (c & 1) * 64;
                const int* idx = (c < 2) ? sE : rN;
#pragma unroll
                for (int i = 0; i < 2; ++i) {
                    int u = tid + i * THREADS;
                    int row = u >> 3, sl = u & 7;
                    int sm = sl ^ (row & 7);
                    int node = idx[row];
                    gl_lds16(xh + (size_t)node * NODE_DIM + kcol + sm * 8, &As[u * 8]);
                }
            } else {
#pragma unroll
                for (int i = 0; i < 2; ++i) {
                    int u = tid + i * THREADS;
                    int row = u >> 3, sl = u & 7;
                    int sm = sl ^ (row & 7);
                    const float* s = ef + (size_t)eID[row] * EDGE_DIM + sm * 8;
                    float4 f0 = ((const float4*)s)[0];
                    float4 f1 = ((const float4*)s)[1];
                    uint4 v;
                    v.x = (unsigned)f2h(f0.x) | ((unsigned)f2h(f0.y) << 16);
                    v.y = (unsigned)f2h(f0.z) | ((unsigned)f2h(f0.w) << 16);
                    v.z = (unsigned)f2h(f1.x) | ((unsigned)f2h(f1.y) << 16);
                    v.w = (unsigned)f2h(f1.z) | ((unsigned)f2h(f1.w) << 16);
                    *(uint4*)(&As[u * 8]) = v;
                }
            }
            // ---- stage B: 256 rows x 64 k ----
            {
                const int kOff = c * BK;
#pragma unroll
                for (int i = 0; i < 4; ++i) {
                    int u = tid + i * THREADS;
                    int n = u >> 3, sl = u & 7;
                    int sm = sl ^ (n & 7);
                    gl_lds16(Wc + n * KDIM + kOff + sm * 8, &Bs[u * 8]);
                }
            }
            __syncthreads();
            // ---- compute ----
#pragma unroll
            for (int ks8 = 0; ks8 < 8; ks8 += 4) {
                half8 a[4], b[4];
#pragma unroll
                for (int mt = 0; mt < 4; ++mt) {
                    int r = wm * 64 + mt * 16 + l16;
                    a[mt] = *(const half8*)(&As[r * BK + (((ks8 + q) ^ (r & 7)) << 3)]);
                }
                const int nb0 = wn * 32;
                const int nbase[4] = { nb0, nb0 + 16, 128 + nb0, 128 + nb0 + 16 };
#pragma unroll
                for (int nt = 0; nt < 4; ++nt) {
                    int n = nbase[nt] + l16;
                    b[nt] = *(const half8*)(&Bs[n * BK + (((ks8 + q) ^ (n & 7)) << 3)]);
                }
#pragma unroll
                for (int mt = 0; mt < 4; ++mt)
#pragma unroll
                    for (int nt = 0; nt < 4; ++nt)
                        acc[mt][nt] = __builtin_amdgcn_mfma_f32_16x16x32_f16(
                            a[mt], b[nt], acc[mt][nt], 0, 0, 0);
            }
        }

        // ---- per-chunk epilogue: activation + run-merged LDS reduction ----
#pragma unroll
        for (int mt = 0; mt < 4; ++mt) {
            int ln4[4];
#pragma unroll
            for (int r = 0; r < 4; ++r)
                ln4[r] = lnE[wm * 64 + mt * 16 + q * 4 + r];
#pragma unroll
            for (int ct = 0; ct < 2; ++ct) {
                const int col = wn * 32 + ct * 16 + l16;
                const float bv = bval[col];
                const float bm = bmul[col];
                int pln = -1;
                float sum = 0.f;
#pragma unroll
                for (int r = 0; r < 4; ++r) {
                    float v = acc[mt][ct][r] + bv;
                    float g = acc[mt][ct + 2][r] + bm;
                    float sp  = fmaxf(v, 0.f) + __logf(1.f + __expf(-fabsf(v)));
                    float sig = __builtin_amdgcn_rcpf(1.f + __expf(-g));
                    float msg = sp * sig;
                    int ln = ln4[r];
                    if (ln != pln) {
                        if (pln >= 0) atomicAdd(&accS[pln * ACCS + col], sum);
                        sum = 0.f;
                        pln = ln;
                    }
                    if (ln >= 0) sum += msg;
                }
                if (pln >= 0) atomicAdd(&accS[pln * ACCS + col], sum);
            }
        }
    }

    // ---- write owned tile (once, no atomics) ----
    __syncthreads();
#pragma unroll
    for (int i = 0; i < 8; ++i) {
        int u = tid + i * THREADS;          // 0..4095
        int nl = u >> 7, col = u & 127;
        int node = nodeBase + nl;
        if (node < NN_NODES) out[(size_t)node * NODE_DIM + col] = accS[nl * ACCS + col];
    }
}

extern "C" void kernel_launch(void* const* d_in, const int* in_sizes, int n_in,
                              void* d_out, int out_size, void* d_ws, size_t ws_size,
                              hipStream_t stream) {
    const float* x  = (const float*)d_in[0];
    const int*   ei = (const int*)d_in[1];
    const float* ef = (const float*)d_in[2];
    const float* Wv = (const float*)d_in[3];
    const float* bv = (const float*)d_in[4];
    const float* Wm = (const float*)d_in[5];
    const float* bm = (const float*)d_in[6];
    float* out = (float*)d_out;

    char* w = (char*)d_ws;
    unsigned short* xh      = (unsigned short*)(w);                    // 12,800,000 B
    unsigned short* Wc      = (unsigned short*)(w + 12800000);         //    163,840 B
    int*            hist    = (int*)(w + 12963840);                    //    200,192 B (NPAD)
    int*            row_ptr = (int*)(w + 13164032);                    //    200,256 B (NPAD+1, padded)
    int*            nxt     = (int*)(w + 13364288);                    //    200,192 B
    int*            perm    = (int*)(w + 13564480);                    //  3,200,000 B
    // total 16,764,480 B

    hipMemsetAsync(hist, 0, NPAD * sizeof(int), stream);

    const int n4x = (NN_NODES * NODE_DIM) / 4;
    const int n4w = (2 * NODE_DIM * KDIM) / 4;
    cast_all_kernel<<<(n4x + n4w + 255) / 256, 256, 0, stream>>>(x, Wv, Wm, xh, Wc);

    hist_kernel<<<E_EDGES / 256, 256, 0, stream>>>(ei, hist);
    scan_kernel<<<1, 1024, 0, stream>>>(hist, row_ptr, nxt);
    scatter_kernel<<<E_EDGES / 256, 256, 0, stream>>>(ei, nxt, perm);

    cgc_main<<<NBLOCKS, THREADS, 0, stream>>>(xh, ei, ef, Wc, bv, bm,
                                              row_ptr, perm, out);
}